// Round 19
// baseline (137.171 us; speedup 1.0000x reference)
//
#include <hip/hip_runtime.h>
#include <hip/hip_fp16.h>

#define NN 50000
#define NE 800000
#define NB 16384

#define NBKT 784          // buckets of 64 node ids (784*64 = 50176 >= NN)
#define BCAP 1280         // per-bucket capacity (mean 1020, +8 sigma)
#define CAPL 8            // LDS staging depth per bucket per binning block
#define P1B  256          // binning blocks
#define DNNB 256          // DNN gemm blocks (64 rows each)

typedef unsigned int uint;
typedef unsigned short ushort;
typedef unsigned char uchar;

__device__ __forceinline__ uint pack2h(float a, float b) {
    return (uint)__half_as_ushort(__float2half_rn(a)) |
           ((uint)__half_as_ushort(__float2half_rn(b)) << 16);
}
__device__ __forceinline__ float h2f(ushort u) {
    return __half2float(__ushort_as_half(u));
}

// ---- fp8 OCP e4m3fn, manual encode (RNE) / decode -----------------------------
__device__ __forceinline__ uint fp8enc(float v) {
    uint b = __float_as_uint(v);
    uint s = b >> 31;
    float a = __uint_as_float(b & 0x7fffffffu);
    int Ei = (int)((b >> 23) & 255u) - 127;
    if (Ei < -6) Ei = -6;
    float qinv = __uint_as_float((uint)(130 - Ei) << 23);   // 2^(3-Ei)
    int mt = (int)rintf(a * qinv);                           // 0..16
    if (mt >= 16) { mt = 8; Ei += 1; }                       // mantissa carry
    uint e8, m;
    if (mt >= 8) { e8 = (uint)(Ei + 7); m = (uint)(mt - 8); }
    else         { e8 = 0u;             m = (uint)mt; }      // subnormal
    return (s << 7) | (e8 << 3) | m;
}
__device__ __forceinline__ float fp8dec(uint u) {
    uint e = (u >> 3) & 15u, m = u & 7u;
    float magn = __uint_as_float(((e + 120u) << 23) | (m << 20));
    float mags = (float)m * 0.001953125f;                    // m * 2^-9
    float mag = (e != 0u) ? magn : mags;
    return (u & 128u) ? -mag : mag;
}

// ---------------- zero the counters (runtime fill kernel is pathological) ------
__global__ void zero_kernel(int* __restrict__ p, int n)
{
    for (int i = threadIdx.x; i < n; i += 256) p[i] = 0;
}

// ---------------- megakernel: bin (2-pass) + DNN GEMM(+BN) + GCN GEMM ----------
// Blocks [0,256): binning ; [256,512): DNN ; [512,1296): GCN1. All independent.
struct BinSh {
    uint st[NBKT * CAPL];                       // 25 KiB
    int lc[NBKT];                               // 3.1 KiB
};
union MegaSh {
    BinSh b;                                    // 28.2 KiB
    float xs[64 * 65];                          // 16.6 KiB (GEMM branches)
};

__global__ __launch_bounds__(512) void mega(const int* __restrict__ ei,
    uint* __restrict__ bufC, uint* __restrict__ bufR,
    int* __restrict__ gcurC, int* __restrict__ gcurR,
    const float* __restrict__ X1, const float* __restrict__ Wd,
    float* __restrict__ H, float* __restrict__ bnsum,
    float* __restrict__ bnsumsq,
    const float* __restrict__ X2, const float* __restrict__ W1,
    ushort* __restrict__ Hh)
{
    __shared__ MegaSh sh;
    const int tid = threadIdx.x;
    const int lane = tid & 63;
    const int wv = __builtin_amdgcn_readfirstlane(tid >> 6);   // 0..7

    if (blockIdx.x < P1B) {
        BinSh& B = sh.b;
        const int per = (NE + P1B - 1) / P1B;
        const int lo = blockIdx.x * per;
        const int hi = (lo + per < NE) ? lo + per : NE;
        // ---- pass 1: bin by col>>6, ent = (r<<6)|(c&63) ----
        for (int i = tid; i < NBKT; i += 512) B.lc[i] = 0;
        __syncthreads();
        for (int e = lo + tid; e < hi; e += 512) {
            int r = ei[e], c = ei[NE + e];
            uint ent = ((uint)r << 6) | (uint)(c & 63);
            int b = c >> 6;
            int pos = atomicAdd(&B.lc[b], 1);
            if (pos < CAPL) B.st[b * CAPL + pos] = ent;
            else { int gp = atomicAdd(&gcurC[b], 1); bufC[(size_t)b * BCAP + gp] = ent; }
        }
        __syncthreads();
        for (int base = wv * 8; base < NBKT; base += 64) {
            int wb = base + (lane >> 3);
            int idx = lane & 7;
            int n = B.lc[wb]; if (n > CAPL) n = CAPL;
            int gb = 0;
            if (idx == 0 && n > 0) gb = atomicAdd(&gcurC[wb], n);
            gb = __shfl(gb, lane & 56);
            if (idx < n) bufC[(size_t)wb * BCAP + gb + idx] = B.st[wb * CAPL + idx];
        }
        __syncthreads();
        // ---- pass 2: bin by row>>6, ent = ((r&63)<<16)|c ----
        for (int i = tid; i < NBKT; i += 512) B.lc[i] = 0;
        __syncthreads();
        for (int e = lo + tid; e < hi; e += 512) {
            int r = ei[e], c = ei[NE + e];
            uint ent = ((uint)(r & 63) << 16) | (uint)c;
            int rb = r >> 6;
            int pos = atomicAdd(&B.lc[rb], 1);
            if (pos < CAPL) B.st[rb * CAPL + pos] = ent;
            else { int gp = atomicAdd(&gcurR[rb], 1); bufR[(size_t)rb * BCAP + gp] = ent; }
        }
        __syncthreads();
        for (int base = wv * 8; base < NBKT; base += 64) {
            int wb = base + (lane >> 3);
            int idx = lane & 7;
            int n = B.lc[wb]; if (n > CAPL) n = CAPL;
            int gb = 0;
            if (idx == 0 && n > 0) gb = atomicAdd(&gcurR[wb], n);
            gb = __shfl(gb, lane & 56);
            if (idx < n) bufR[(size_t)wb * BCAP + gb + idx] = B.st[wb * CAPL + idx];
        }
        return;
    }

    if (blockIdx.x < P1B + DNNB) {
        // ---- DNN: 64 rows, K=256 in 4 staged chunks, lane = row, 8 waves ----
        float* xs = sh.xs;
        const int c0 = wv * 8;
        const int row0 = (blockIdx.x - P1B) * 64;
        float acc[8];
#pragma unroll
        for (int j = 0; j < 8; ++j) acc[j] = 0.f;
#pragma unroll 1
        for (int chunk = 0; chunk < 4; ++chunk) {
            if (chunk) __syncthreads();
            for (int i = tid; i < 4096; i += 512) {
                int r = i >> 6, k = i & 63;
                xs[r * 65 + k] = X1[(size_t)(row0 + r) * 256 + chunk * 64 + k];
            }
            __syncthreads();
            const float* xrow = xs + lane * 65;
#pragma unroll
            for (int k4 = 0; k4 < 16; ++k4) {
                float x0 = xrow[4 * k4 + 0];
                float x1 = xrow[4 * k4 + 1];
                float x2 = xrow[4 * k4 + 2];
                float x3 = xrow[4 * k4 + 3];
                const float* wr = Wd + (size_t)(chunk * 64 + 4 * k4) * 64 + c0;
#pragma unroll
                for (int j = 0; j < 8; ++j) {
                    float a = acc[j];
                    a = fmaf(x0, wr[j],       a);
                    a = fmaf(x1, wr[64 + j],  a);
                    a = fmaf(x2, wr[128 + j], a);
                    a = fmaf(x3, wr[192 + j], a);
                    acc[j] = a;
                }
            }
        }
        __syncthreads();
#pragma unroll
        for (int j = 0; j < 8; ++j) xs[lane * 65 + c0 + j] = acc[j];
        __syncthreads();
        float s = 0.f, q = 0.f;
        for (int i = tid; i < 4096; i += 512) {
            int r = i >> 6, c = i & 63;
            float v = xs[r * 65 + c];
            H[(size_t)(row0 + r) * 64 + c] = v;
            s += v; q += v * v;
        }
        __syncthreads();
        float* red = xs;
        red[tid] = s; red[512 + tid] = q;
        __syncthreads();
        if (tid < 64) {
            float ss = 0.f, qq = 0.f;
#pragma unroll
            for (int gidx = 0; gidx < 8; ++gidx) {
                ss += red[gidx * 64 + tid];
                qq += red[512 + gidx * 64 + tid];
            }
            atomicAdd(&bnsum[tid], ss);
            atomicAdd(&bnsumsq[tid], qq);
        }
        return;
    }

    // ---- GCN1: h1h = fp16(x2 @ g1W) UNSCALED, K=64, lane = row, 8 waves ----
    {
        float* xs = sh.xs;
        const int c0 = wv * 8;
        const int row0 = (blockIdx.x - P1B - DNNB) * 64;
        float acc[8];
#pragma unroll
        for (int j = 0; j < 8; ++j) acc[j] = 0.f;
        if (row0 + 64 <= NN) {
            for (int i = tid; i < 4096; i += 512) {
                int r = i >> 6, k = i & 63;
                xs[r * 65 + k] = X2[(size_t)(row0 + r) * 64 + k];
            }
        } else {
            for (int i = tid; i < 4096; i += 512) {
                int r = i >> 6, k = i & 63;
                xs[r * 65 + k] = (row0 + r < NN)
                               ? X2[(size_t)(row0 + r) * 64 + k] : 0.f;
            }
        }
        __syncthreads();
        const float* xrow = xs + lane * 65;
#pragma unroll
        for (int k4 = 0; k4 < 16; ++k4) {
            float x0 = xrow[4 * k4 + 0];
            float x1 = xrow[4 * k4 + 1];
            float x2 = xrow[4 * k4 + 2];
            float x3 = xrow[4 * k4 + 3];
            const float* wr = W1 + (size_t)(4 * k4) * 64 + c0;
#pragma unroll
            for (int j = 0; j < 8; ++j) {
                float a = acc[j];
                a = fmaf(x0, wr[j],       a);
                a = fmaf(x1, wr[64 + j],  a);
                a = fmaf(x2, wr[128 + j], a);
                a = fmaf(x3, wr[192 + j], a);
                acc[j] = a;
            }
        }
        __syncthreads();
#pragma unroll
        for (int j = 0; j < 8; ++j) xs[lane * 65 + c0 + j] = acc[j];
        __syncthreads();
        for (int i = tid; i < 2048; i += 512) {
            int r = i >> 5, cp = (i & 31) * 2;
            int row = row0 + r;
            if (row < NN) {
                uint v = pack2h(xs[r * 65 + cp], xs[r * 65 + cp + 1]);
                *reinterpret_cast<uint*>(Hh + (size_t)row * 64 + cp) = v;
            }
        }
    }
}

// ---------------- histogram -> dis, cnth; convert h1h(fp16) -> h8 = fp8(S*dis*h1)
__global__ __launch_bounds__(256) void cnt_dis_cvt(const uint* __restrict__ bufC,
    const int* __restrict__ gcurC, const ushort* __restrict__ Hh,
    uchar* __restrict__ h8, float* __restrict__ dis, int* __restrict__ cnth)
{
    __shared__ int hist[64];
    __shared__ float dsc[64];                   // S * dis per row, S = 16
    const int tid = threadIdx.x, bb = blockIdx.x;
    const int row0 = bb * 64;
    if (tid < 64) hist[tid] = 0;
    __syncthreads();
    const int n = gcurC[bb];
    const uint* src = bufC + (size_t)bb * BCAP;
    for (int i = tid; i < n; i += 256) atomicAdd(&hist[src[i] & 63], 1);
    __syncthreads();
    if (tid < 64) {
        int c = row0 + tid;
        cnth[row0 + tid] = hist[tid];
        float d = rsqrtf((float)hist[tid] + 1.0f);
        dsc[tid] = 16.0f * d;
        if (c < NN) dis[c] = d;
    }
    __syncthreads();
    // convert this block's 64 rows: 4 fp16 -> 4 fp8 per thread-iter
    for (int i = tid; i < 1024; i += 256) {
        int r = i >> 4, c4 = (i & 15) << 2;
        int row = row0 + r;
        if (row < NN) {
            uint2 hv = *reinterpret_cast<const uint2*>(Hh + (size_t)row * 64 + c4);
            float sd = dsc[r];
            uint b0 = fp8enc(sd * h2f((ushort)(hv.x & 0xffffu)));
            uint b1 = fp8enc(sd * h2f((ushort)(hv.x >> 16)));
            uint b2 = fp8enc(sd * h2f((ushort)(hv.y & 0xffffu)));
            uint b3 = fp8enc(sd * h2f((ushort)(hv.y >> 16)));
            *reinterpret_cast<uint*>(h8 + (size_t)row * 64 + c4) =
                b0 | (b1 << 8) | (b2 << 16) | (b3 << 24);
        }
    }
}

// ---------------- gather (8 edges/VMEM-instr, fp8 rows) + wraw + epilogue ------
// g_c = (dis_c/S)*(sum_in h8_r + h8_c) + b1 ; coef_c = dis_c*w_c + dis_c^2
__global__ __launch_bounds__(512) void gather_pass(const uint* __restrict__ bufC,
    const int* __restrict__ gcurC, const int* __restrict__ cnth,
    const uint* __restrict__ bufR, const int* __restrict__ gcurR,
    const float* __restrict__ dis, const uchar* __restrict__ h8,
    const float* __restrict__ b1, float* __restrict__ svec)
{
    __shared__ int sorted[BCAP];
    __shared__ int cntS[64], offsS[64], curS[64];
    __shared__ float w[64];
    __shared__ float red[8][64];
    const int tid = threadIdx.x;
    const int lane = tid & 63;
    const int wv = __builtin_amdgcn_readfirstlane(tid >> 6);   // 0..7
    const int bb = blockIdx.x;
    const int g8 = lane >> 3;                    // edge sub-group 0..7
    const int l8 = lane & 7;                     // col-octet index
    if (tid < 64) {                              // wave 0: load hist + 64-wide scan
        w[tid] = 0.f;
        int v = cnth[bb * 64 + tid];
        cntS[tid] = v;
        int s = v;
#pragma unroll
        for (int o = 1; o < 64; o <<= 1) {
            int u = __shfl_up(s, o);
            if (lane >= o) s += u;
        }
        offsS[tid] = s - v;
        curS[tid] = s - v;
    }
    __syncthreads();
    // wraw accumulation from the row-bucket (dis is a 200 KB L2-resident table)
    const int n2 = gcurR[bb];
    const uint* srcR = bufR + (size_t)bb * BCAP;
    for (int i = tid; i < n2; i += 512) {
        uint e = srcR[i];
        atomicAdd(&w[e >> 16], dis[e & 0xffffu]);
    }
    // LDS counting-sort scatter of the col-bucket
    const int n = gcurC[bb];
    const uint* src = bufC + (size_t)bb * BCAP;
    for (int i = tid; i < n; i += 512) {
        uint e = src[i];
        int p = atomicAdd(&curS[e & 63u], 1);
        sorted[p] = (int)(e >> 6);
    }
    __syncthreads();
    // each wave: 8 consecutive nodes; 16 edges/iter, uint2 (8 fp8 cols)/lane
    float s0a = 0.f, s1a = 0.f, s2a = 0.f, s3a = 0.f;
    float s4a = 0.f, s5a = 0.f, s6a = 0.f, s7a = 0.f;
    const float4 blv0 = *reinterpret_cast<const float4*>(b1 + (l8 << 3));
    const float4 blv1 = *reinterpret_cast<const float4*>(b1 + (l8 << 3) + 4);
#pragma unroll 1
    for (int t = 0; t < 8; ++t) {
        const int nd = wv * 8 + t;
        const int lo = offsS[nd], hi2 = lo + cntS[nd];
        float a0 = 0.f, a1 = 0.f, a2 = 0.f, a3 = 0.f;
        float a4 = 0.f, a5 = 0.f, a6 = 0.f, a7 = 0.f;
        for (int e = lo; e < hi2; e += 16) {
            int i0 = e + g8;
            int i1 = e + 8 + g8;
            int j0 = (i0 < hi2) ? i0 : hi2 - 1;
            int j1 = (i1 < hi2) ? i1 : hi2 - 1;
            float m0 = (i0 < hi2) ? 1.f : 0.f;
            float m1 = (i1 < hi2) ? 1.f : 0.f;
            int r0 = sorted[j0];
            int r1 = sorted[j1];
            uint2 v0 = *reinterpret_cast<const uint2*>(h8 + ((size_t)r0 << 6) + (l8 << 3));
            uint2 v1 = *reinterpret_cast<const uint2*>(h8 + ((size_t)r1 << 6) + (l8 << 3));
            a0 = fmaf(m0, fp8dec(v0.x),        a0);
            a1 = fmaf(m0, fp8dec(v0.x >> 8),   a1);
            a2 = fmaf(m0, fp8dec(v0.x >> 16),  a2);
            a3 = fmaf(m0, fp8dec(v0.x >> 24),  a3);
            a4 = fmaf(m0, fp8dec(v0.y),        a4);
            a5 = fmaf(m0, fp8dec(v0.y >> 8),   a5);
            a6 = fmaf(m0, fp8dec(v0.y >> 16),  a6);
            a7 = fmaf(m0, fp8dec(v0.y >> 24),  a7);
            a0 = fmaf(m1, fp8dec(v1.x),        a0);
            a1 = fmaf(m1, fp8dec(v1.x >> 8),   a1);
            a2 = fmaf(m1, fp8dec(v1.x >> 16),  a2);
            a3 = fmaf(m1, fp8dec(v1.x >> 24),  a3);
            a4 = fmaf(m1, fp8dec(v1.y),        a4);
            a5 = fmaf(m1, fp8dec(v1.y >> 8),   a5);
            a6 = fmaf(m1, fp8dec(v1.y >> 16),  a6);
            a7 = fmaf(m1, fp8dec(v1.y >> 24),  a7);
        }
        // combine the 8 edge sub-groups (butterfly over lane bits 3..5)
        a0 += __shfl_xor(a0, 8);  a0 += __shfl_xor(a0, 16); a0 += __shfl_xor(a0, 32);
        a1 += __shfl_xor(a1, 8);  a1 += __shfl_xor(a1, 16); a1 += __shfl_xor(a1, 32);
        a2 += __shfl_xor(a2, 8);  a2 += __shfl_xor(a2, 16); a2 += __shfl_xor(a2, 32);
        a3 += __shfl_xor(a3, 8);  a3 += __shfl_xor(a3, 16); a3 += __shfl_xor(a3, 32);
        a4 += __shfl_xor(a4, 8);  a4 += __shfl_xor(a4, 16); a4 += __shfl_xor(a4, 32);
        a5 += __shfl_xor(a5, 8);  a5 += __shfl_xor(a5, 16); a5 += __shfl_xor(a5, 32);
        a6 += __shfl_xor(a6, 8);  a6 += __shfl_xor(a6, 16); a6 += __shfl_xor(a6, 32);
        a7 += __shfl_xor(a7, 8);  a7 += __shfl_xor(a7, 16); a7 += __shfl_xor(a7, 32);
        const int c = bb * 64 + nd;
        if (c < NN) {
            float d = dis[c];
            float dS = d * 0.0625f;              // dis / S, S = 16
            float coef = fmaf(d, w[nd], d * d);
            uint2 sv = *reinterpret_cast<const uint2*>(h8 + ((size_t)c << 6) + (l8 << 3));
            float g0 = fmaf(dS, a0 + fp8dec(sv.x),       blv0.x);
            float g1 = fmaf(dS, a1 + fp8dec(sv.x >> 8),  blv0.y);
            float g2 = fmaf(dS, a2 + fp8dec(sv.x >> 16), blv0.z);
            float g3 = fmaf(dS, a3 + fp8dec(sv.x >> 24), blv0.w);
            float g4 = fmaf(dS, a4 + fp8dec(sv.y),       blv1.x);
            float g5 = fmaf(dS, a5 + fp8dec(sv.y >> 8),  blv1.y);
            float g6 = fmaf(dS, a6 + fp8dec(sv.y >> 16), blv1.z);
            float g7 = fmaf(dS, a7 + fp8dec(sv.y >> 24), blv1.w);
            s0a = fmaf(coef, fmaxf(g0, 0.f), s0a);
            s1a = fmaf(coef, fmaxf(g1, 0.f), s1a);
            s2a = fmaf(coef, fmaxf(g2, 0.f), s2a);
            s3a = fmaf(coef, fmaxf(g3, 0.f), s3a);
            s4a = fmaf(coef, fmaxf(g4, 0.f), s4a);
            s5a = fmaf(coef, fmaxf(g5, 0.f), s5a);
            s6a = fmaf(coef, fmaxf(g6, 0.f), s6a);
            s7a = fmaf(coef, fmaxf(g7, 0.f), s7a);
        }
    }
    if (g8 == 0) {
        red[wv][(l8 << 3) + 0] = s0a;
        red[wv][(l8 << 3) + 1] = s1a;
        red[wv][(l8 << 3) + 2] = s2a;
        red[wv][(l8 << 3) + 3] = s3a;
        red[wv][(l8 << 3) + 4] = s4a;
        red[wv][(l8 << 3) + 5] = s5a;
        red[wv][(l8 << 3) + 6] = s6a;
        red[wv][(l8 << 3) + 7] = s7a;
    }
    __syncthreads();
    if (wv == 0) {
        float s = ((red[0][lane] + red[1][lane]) + (red[2][lane] + red[3][lane])) +
                  ((red[4][lane] + red[5][lane]) + (red[6][lane] + red[7][lane]));
        atomicAdd(&svec[lane], s);
    }
}

// ---------------- output + fused finalize --------------------------------------
__global__ __launch_bounds__(256) void out_final(const float* __restrict__ H,
    const float* __restrict__ bnsum, const float* __restrict__ bnsumsq,
    const float* __restrict__ gamma, const float* __restrict__ beta,
    const float* __restrict__ svec, const float* __restrict__ g2W,
    const float* __restrict__ g2b, const float* __restrict__ fc1W,
    const float* __restrict__ fc1b, const float* __restrict__ fc2W,
    const float* __restrict__ fc2b, float* __restrict__ out)
{
    __shared__ float scaleS[64], shiftS[64], vdnnS[64];
    __shared__ float consS;
    const int tid = threadIdx.x;
    const int lane = tid & 63;
    const int grp = tid >> 6;
    if (tid < 64) {                              // wave 0 computes finalize
        int j = tid;
        float mu = bnsum[j] * (1.0f / NB);
        float var = bnsumsq[j] * (1.0f / NB) - mu * mu;
        float sc = rsqrtf(var + 1e-5f) * gamma[j];
        scaleS[j] = sc;
        shiftS[j] = beta[j] - mu * sc;
        float ge = 0.f;
        for (int k = 0; k < 64; ++k) ge += svec[k] * g2W[k * 64 + j];
        ge = ge * (1.0f / NN) + g2b[j];
        float vd = 0.f, vg = 0.f;
        for (int k = 0; k < 64; ++k) {
            vd += fc1W[j * 64 + k] * fc2W[k];
            vg += fc1W[(64 + j) * 64 + k] * fc2W[k];
        }
        vdnnS[j] = vd;
        float part = ge * vg + fc1b[j] * fc2W[j];
#pragma unroll
        for (int o = 32; o > 0; o >>= 1) part += __shfl_down(part, o);
        if (j == 0) consS = part + fc2b[0];
    }
    __syncthreads();
    const float sc = scaleS[lane], sh = shiftS[lane], vd = vdnnS[lane];
    const float C = consS;
#pragma unroll 1
    for (int t = 0; t < 8; ++t) {
        int i = blockIdx.x * 32 + grp * 8 + t;
        float x = H[(size_t)i * 64 + lane] * sc + sh;
        x = fmaxf(x, 0.f) * vd;
#pragma unroll
        for (int o = 32; o > 0; o >>= 1) x += __shfl_down(x, o);
        if (lane == 0) out[i] = x + C;
    }
}

extern "C" void kernel_launch(void* const* d_in, const int* in_sizes, int n_in,
                              void* d_out, int out_size, void* d_ws, size_t ws_size,
                              hipStream_t stream)
{
    const float* x1    = (const float*)d_in[0];
    const float* x2    = (const float*)d_in[1];
    const int*   ei    = (const int*)d_in[2];
    const float* dnnW  = (const float*)d_in[3];
    // d_in[4] = dnn_b: cancels inside BatchNorm, unused
    const float* gamma = (const float*)d_in[5];
    const float* beta  = (const float*)d_in[6];
    const float* g1W   = (const float*)d_in[7];
    const float* g1b   = (const float*)d_in[8];
    const float* g2W   = (const float*)d_in[9];
    const float* g2b   = (const float*)d_in[10];
    const float* fc1W  = (const float*)d_in[11];
    const float* fc1b  = (const float*)d_in[12];
    const float* fc2W  = (const float*)d_in[13];
    const float* fc2b  = (const float*)d_in[14];

    float* ws      = (float*)d_ws;
    ushort* h1h    = (ushort*)ws;                 // 50176*64 ushorts = 1,605,632 f
    float* hdnn    = ws + 1605632;                // 1,048,576 f
    float* dis     = hdnn + 1048576;              // 50,176 f
    int*   cnth    = (int*)(dis + 50176 + 25088); // 50,176 i (keeps old layout)
    uint*  bufC    = (uint*)(cnth + 50176);       // 784*1280 = 1,003,520
    uint*  bufR    = bufC + NBKT * BCAP;          // 1,003,520
    int*   gcurC   = (int*)(bufR + NBKT * BCAP);  // 784   <- zero region start
    int*   gcurR   = gcurC + NBKT;                // 784
    float* bnsum   = (float*)(gcurR + NBKT);      // 64
    float* bnsumsq = bnsum + 64;                  // 64
    float* svec    = bnsumsq + 64;                // 64    <- zero region end (1760)
    uchar* h8      = (uchar*)(svec + 64);         // 50176*64 B = 802,816 f

    zero_kernel<<<1, 256, 0, stream>>>(gcurC, NBKT * 2 + 192);

    mega<<<P1B + DNNB + NBKT, 512, 0, stream>>>(ei, bufC, bufR, gcurC, gcurR,
                                                x1, dnnW, hdnn, bnsum, bnsumsq,
                                                x2, g1W, h1h);
    cnt_dis_cvt<<<NBKT, 256, 0, stream>>>(bufC, gcurC, h1h, h8, dis, cnth);
    gather_pass<<<NBKT, 512, 0, stream>>>(bufC, gcurC, cnth, bufR, gcurR,
                                          dis, h8, g1b, svec);
    out_final<<<512, 256, 0, stream>>>(hdnn, bnsum, bnsumsq, gamma, beta, svec,
                                       g2W, g2b, fc1W, fc1b, fc2W, fc2b,
                                       (float*)d_out);
}

// Round 20
// 106.931 us; speedup vs baseline: 1.2828x; 1.2828x over previous
//
#include <hip/hip_runtime.h>
#include <hip/hip_fp16.h>

#define NN 50000
#define NE 800000
#define NB 16384

#define NBKT 784          // buckets of 64 node ids (784*64 = 50176 >= NN)
#define BCAP 1280         // per-bucket capacity (mean 1020, +8 sigma)
#define CAPL 8            // LDS staging depth per bucket per binning block
#define P1B  256          // binning blocks
#define DNNB 256          // DNN gemm blocks (64 rows each)

typedef unsigned int uint;
typedef unsigned short ushort;

__device__ __forceinline__ uint pack2h(float a, float b) {
    return (uint)__half_as_ushort(__float2half_rn(a)) |
           ((uint)__half_as_ushort(__float2half_rn(b)) << 16);
}
__device__ __forceinline__ float h2f(ushort u) {
    return __half2float(__ushort_as_half(u));
}

// ---------------- zero the counters (runtime fill kernel is pathological) ------
__global__ void zero_kernel(int* __restrict__ p, int n)
{
    for (int i = threadIdx.x; i < n; i += 256) p[i] = 0;
}

// ---------------- megakernel: bin (2-pass) + DNN GEMM(+BN) + GCN GEMM ----------
// Blocks [0,256): binning ; [256,512): DNN ; [512,1296): GCN1. All independent.
struct BinSh {
    uint st[NBKT * CAPL];                       // 25 KiB
    int lc[NBKT];                               // 3.1 KiB
};
union MegaSh {
    BinSh b;                                    // 28.2 KiB
    float xs[64 * 65];                          // 16.6 KiB (GEMM branches)
};

__global__ __launch_bounds__(512) void mega(const int* __restrict__ ei,
    uint* __restrict__ bufC, uint* __restrict__ bufR,
    int* __restrict__ gcurC, int* __restrict__ gcurR,
    const float* __restrict__ X1, const float* __restrict__ Wd,
    float* __restrict__ H, float* __restrict__ bnsum,
    float* __restrict__ bnsumsq,
    const float* __restrict__ X2, const float* __restrict__ W1,
    ushort* __restrict__ Hh)
{
    __shared__ MegaSh sh;
    const int tid = threadIdx.x;
    const int lane = tid & 63;
    const int wv = __builtin_amdgcn_readfirstlane(tid >> 6);   // 0..7

    if (blockIdx.x < P1B) {
        BinSh& B = sh.b;
        const int per = (NE + P1B - 1) / P1B;
        const int lo = blockIdx.x * per;
        const int hi = (lo + per < NE) ? lo + per : NE;
        // ---- pass 1: bin by col>>6, ent = (r<<6)|(c&63) ----
        for (int i = tid; i < NBKT; i += 512) B.lc[i] = 0;
        __syncthreads();
        for (int e = lo + tid; e < hi; e += 512) {
            int r = ei[e], c = ei[NE + e];
            uint ent = ((uint)r << 6) | (uint)(c & 63);
            int b = c >> 6;
            int pos = atomicAdd(&B.lc[b], 1);
            if (pos < CAPL) B.st[b * CAPL + pos] = ent;
            else { int gp = atomicAdd(&gcurC[b], 1); bufC[(size_t)b * BCAP + gp] = ent; }
        }
        __syncthreads();
        for (int base = wv * 8; base < NBKT; base += 64) {
            int wb = base + (lane >> 3);
            int idx = lane & 7;
            int n = B.lc[wb]; if (n > CAPL) n = CAPL;
            int gb = 0;
            if (idx == 0 && n > 0) gb = atomicAdd(&gcurC[wb], n);
            gb = __shfl(gb, lane & 56);
            if (idx < n) bufC[(size_t)wb * BCAP + gb + idx] = B.st[wb * CAPL + idx];
        }
        __syncthreads();
        // ---- pass 2: bin by row>>6, ent = ((r&63)<<16)|c ----
        for (int i = tid; i < NBKT; i += 512) B.lc[i] = 0;
        __syncthreads();
        for (int e = lo + tid; e < hi; e += 512) {
            int r = ei[e], c = ei[NE + e];
            uint ent = ((uint)(r & 63) << 16) | (uint)c;
            int rb = r >> 6;
            int pos = atomicAdd(&B.lc[rb], 1);
            if (pos < CAPL) B.st[rb * CAPL + pos] = ent;
            else { int gp = atomicAdd(&gcurR[rb], 1); bufR[(size_t)rb * BCAP + gp] = ent; }
        }
        __syncthreads();
        for (int base = wv * 8; base < NBKT; base += 64) {
            int wb = base + (lane >> 3);
            int idx = lane & 7;
            int n = B.lc[wb]; if (n > CAPL) n = CAPL;
            int gb = 0;
            if (idx == 0 && n > 0) gb = atomicAdd(&gcurR[wb], n);
            gb = __shfl(gb, lane & 56);
            if (idx < n) bufR[(size_t)wb * BCAP + gb + idx] = B.st[wb * CAPL + idx];
        }
        return;
    }

    if (blockIdx.x < P1B + DNNB) {
        // ---- DNN: 64 rows, K=256 in 4 staged chunks, lane = row, 8 waves ----
        float* xs = sh.xs;
        const int c0 = wv * 8;
        const int row0 = (blockIdx.x - P1B) * 64;
        float acc[8];
#pragma unroll
        for (int j = 0; j < 8; ++j) acc[j] = 0.f;
#pragma unroll 1
        for (int chunk = 0; chunk < 4; ++chunk) {
            if (chunk) __syncthreads();
            for (int i = tid; i < 4096; i += 512) {
                int r = i >> 6, k = i & 63;
                xs[r * 65 + k] = X1[(size_t)(row0 + r) * 256 + chunk * 64 + k];
            }
            __syncthreads();
            const float* xrow = xs + lane * 65;
#pragma unroll
            for (int k4 = 0; k4 < 16; ++k4) {
                float x0 = xrow[4 * k4 + 0];
                float x1 = xrow[4 * k4 + 1];
                float x2 = xrow[4 * k4 + 2];
                float x3 = xrow[4 * k4 + 3];
                const float* wr = Wd + (size_t)(chunk * 64 + 4 * k4) * 64 + c0;
#pragma unroll
                for (int j = 0; j < 8; ++j) {
                    float a = acc[j];
                    a = fmaf(x0, wr[j],       a);
                    a = fmaf(x1, wr[64 + j],  a);
                    a = fmaf(x2, wr[128 + j], a);
                    a = fmaf(x3, wr[192 + j], a);
                    acc[j] = a;
                }
            }
        }
        __syncthreads();
#pragma unroll
        for (int j = 0; j < 8; ++j) xs[lane * 65 + c0 + j] = acc[j];
        __syncthreads();
        float s = 0.f, q = 0.f;
        for (int i = tid; i < 4096; i += 512) {
            int r = i >> 6, c = i & 63;
            float v = xs[r * 65 + c];
            H[(size_t)(row0 + r) * 64 + c] = v;
            s += v; q += v * v;
        }
        __syncthreads();
        float* red = xs;
        red[tid] = s; red[512 + tid] = q;
        __syncthreads();
        if (tid < 64) {
            float ss = 0.f, qq = 0.f;
#pragma unroll
            for (int gidx = 0; gidx < 8; ++gidx) {
                ss += red[gidx * 64 + tid];
                qq += red[512 + gidx * 64 + tid];
            }
            atomicAdd(&bnsum[tid], ss);
            atomicAdd(&bnsumsq[tid], qq);
        }
        return;
    }

    // ---- GCN1: h1h = fp16(x2 @ g1W) UNSCALED, K=64, lane = row, 8 waves ----
    {
        float* xs = sh.xs;
        const int c0 = wv * 8;
        const int row0 = (blockIdx.x - P1B - DNNB) * 64;
        float acc[8];
#pragma unroll
        for (int j = 0; j < 8; ++j) acc[j] = 0.f;
        if (row0 + 64 <= NN) {
            for (int i = tid; i < 4096; i += 512) {
                int r = i >> 6, k = i & 63;
                xs[r * 65 + k] = X2[(size_t)(row0 + r) * 64 + k];
            }
        } else {
            for (int i = tid; i < 4096; i += 512) {
                int r = i >> 6, k = i & 63;
                xs[r * 65 + k] = (row0 + r < NN)
                               ? X2[(size_t)(row0 + r) * 64 + k] : 0.f;
            }
        }
        __syncthreads();
        const float* xrow = xs + lane * 65;
#pragma unroll
        for (int k4 = 0; k4 < 16; ++k4) {
            float x0 = xrow[4 * k4 + 0];
            float x1 = xrow[4 * k4 + 1];
            float x2 = xrow[4 * k4 + 2];
            float x3 = xrow[4 * k4 + 3];
            const float* wr = W1 + (size_t)(4 * k4) * 64 + c0;
#pragma unroll
            for (int j = 0; j < 8; ++j) {
                float a = acc[j];
                a = fmaf(x0, wr[j],       a);
                a = fmaf(x1, wr[64 + j],  a);
                a = fmaf(x2, wr[128 + j], a);
                a = fmaf(x3, wr[192 + j], a);
                acc[j] = a;
            }
        }
        __syncthreads();
#pragma unroll
        for (int j = 0; j < 8; ++j) xs[lane * 65 + c0 + j] = acc[j];
        __syncthreads();
        for (int i = tid; i < 2048; i += 512) {
            int r = i >> 5, cp = (i & 31) * 2;
            int row = row0 + r;
            if (row < NN) {
                uint v = pack2h(xs[r * 65 + cp], xs[r * 65 + cp + 1]);
                *reinterpret_cast<uint*>(Hh + (size_t)row * 64 + cp) = v;
            }
        }
    }
}

// ---------------- per-bucket histogram -> dis, cnth; scale h1h rows in place ---
__global__ __launch_bounds__(256) void cnt_dis_scale(const uint* __restrict__ bufC,
    const int* __restrict__ gcurC, ushort* __restrict__ Hh,
    float* __restrict__ dis, int* __restrict__ cnth)
{
    __shared__ int hist[64];
    __shared__ float disS[64];
    const int tid = threadIdx.x, bb = blockIdx.x;
    const int row0 = bb * 64;
    if (tid < 64) hist[tid] = 0;
    __syncthreads();
    const int n = gcurC[bb];
    const uint* src = bufC + (size_t)bb * BCAP;
    for (int i = tid; i < n; i += 256) atomicAdd(&hist[src[i] & 63], 1);
    __syncthreads();
    if (tid < 64) {
        int c = row0 + tid;
        cnth[row0 + tid] = hist[tid];
        float d = rsqrtf((float)hist[tid] + 1.0f);
        disS[tid] = d;
        if (c < NN) dis[c] = d;
    }
    __syncthreads();
    // scale this block's 64 h1h rows by dis (block owns rows exclusively)
    for (int i = tid; i < 2048; i += 256) {
        int r = i >> 5, cp = (i & 31) * 2;
        int row = row0 + r;
        if (row < NN) {
            uint* p = reinterpret_cast<uint*>(Hh + (size_t)row * 64 + cp);
            uint v = *p;
            float d = disS[r];
            *p = pack2h(d * h2f((ushort)(v & 0xffffu)),
                        d * h2f((ushort)(v >> 16)));
        }
    }
}

// ---------------- gather (8 edges/VMEM-instr, fp16 rows) + wraw + epilogue -----
// g_c = dis_c*(sum_in h1d_r + h1d_c) + b1 ; coef_c = dis_c*w_c + dis_c^2
__global__ __launch_bounds__(512) void gather_pass(const uint* __restrict__ bufC,
    const int* __restrict__ gcurC, const int* __restrict__ cnth,
    const uint* __restrict__ bufR, const int* __restrict__ gcurR,
    const float* __restrict__ dis, const ushort* __restrict__ hs,
    const float* __restrict__ b1, float* __restrict__ svec)
{
    __shared__ int sorted[BCAP];
    __shared__ int cntS[64], offsS[64], curS[64];
    __shared__ float w[64];
    __shared__ float red[8][64];
    const int tid = threadIdx.x;
    const int lane = tid & 63;
    const int wv = __builtin_amdgcn_readfirstlane(tid >> 6);   // 0..7
    const int bb = blockIdx.x;
    const int g8 = lane >> 3;                    // edge sub-group 0..7
    const int l8 = lane & 7;                     // col-octet index
    if (tid < 64) {                              // wave 0: load hist + 64-wide scan
        w[tid] = 0.f;
        int v = cnth[bb * 64 + tid];
        cntS[tid] = v;
        int s = v;
#pragma unroll
        for (int o = 1; o < 64; o <<= 1) {
            int u = __shfl_up(s, o);
            if (lane >= o) s += u;
        }
        offsS[tid] = s - v;
        curS[tid] = s - v;
    }
    __syncthreads();
    // wraw accumulation from the row-bucket (dis is a 200 KB L2-resident table)
    const int n2 = gcurR[bb];
    const uint* srcR = bufR + (size_t)bb * BCAP;
    for (int i = tid; i < n2; i += 512) {
        uint e = srcR[i];
        atomicAdd(&w[e >> 16], dis[e & 0xffffu]);
    }
    // LDS counting-sort scatter of the col-bucket
    const int n = gcurC[bb];
    const uint* src = bufC + (size_t)bb * BCAP;
    for (int i = tid; i < n; i += 512) {
        uint e = src[i];
        int p = atomicAdd(&curS[e & 63u], 1);
        sorted[p] = (int)(e >> 6);
    }
    __syncthreads();
    // each wave: 8 consecutive nodes; 16 edges/iter, uint4 (8 fp16 cols)/lane
    float s0a = 0.f, s1a = 0.f, s2a = 0.f, s3a = 0.f;
    float s4a = 0.f, s5a = 0.f, s6a = 0.f, s7a = 0.f;
    const float4 blv0 = *reinterpret_cast<const float4*>(b1 + (l8 << 3));
    const float4 blv1 = *reinterpret_cast<const float4*>(b1 + (l8 << 3) + 4);
#pragma unroll 1
    for (int t = 0; t < 8; ++t) {
        const int nd = wv * 8 + t;
        const int lo = offsS[nd], hi2 = lo + cntS[nd];
        float a0 = 0.f, a1 = 0.f, a2 = 0.f, a3 = 0.f;
        float a4 = 0.f, a5 = 0.f, a6 = 0.f, a7 = 0.f;
        for (int e = lo; e < hi2; e += 16) {
            int i0 = e + g8;
            int i1 = e + 8 + g8;
            int j0 = (i0 < hi2) ? i0 : hi2 - 1;
            int j1 = (i1 < hi2) ? i1 : hi2 - 1;
            float m0 = (i0 < hi2) ? 1.f : 0.f;
            float m1 = (i1 < hi2) ? 1.f : 0.f;
            int r0 = sorted[j0];
            int r1 = sorted[j1];
            uint4 v0 = *reinterpret_cast<const uint4*>(hs + ((size_t)r0 << 6) + (l8 << 3));
            uint4 v1 = *reinterpret_cast<const uint4*>(hs + ((size_t)r1 << 6) + (l8 << 3));
            a0 = fmaf(m0, h2f((ushort)(v0.x & 0xffffu)), a0);
            a1 = fmaf(m0, h2f((ushort)(v0.x >> 16)),     a1);
            a2 = fmaf(m0, h2f((ushort)(v0.y & 0xffffu)), a2);
            a3 = fmaf(m0, h2f((ushort)(v0.y >> 16)),     a3);
            a4 = fmaf(m0, h2f((ushort)(v0.z & 0xffffu)), a4);
            a5 = fmaf(m0, h2f((ushort)(v0.z >> 16)),     a5);
            a6 = fmaf(m0, h2f((ushort)(v0.w & 0xffffu)), a6);
            a7 = fmaf(m0, h2f((ushort)(v0.w >> 16)),     a7);
            a0 = fmaf(m1, h2f((ushort)(v1.x & 0xffffu)), a0);
            a1 = fmaf(m1, h2f((ushort)(v1.x >> 16)),     a1);
            a2 = fmaf(m1, h2f((ushort)(v1.y & 0xffffu)), a2);
            a3 = fmaf(m1, h2f((ushort)(v1.y >> 16)),     a3);
            a4 = fmaf(m1, h2f((ushort)(v1.z & 0xffffu)), a4);
            a5 = fmaf(m1, h2f((ushort)(v1.z >> 16)),     a5);
            a6 = fmaf(m1, h2f((ushort)(v1.w & 0xffffu)), a6);
            a7 = fmaf(m1, h2f((ushort)(v1.w >> 16)),     a7);
        }
        // combine the 8 edge sub-groups (butterfly over lane bits 3..5)
        a0 += __shfl_xor(a0, 8);  a0 += __shfl_xor(a0, 16); a0 += __shfl_xor(a0, 32);
        a1 += __shfl_xor(a1, 8);  a1 += __shfl_xor(a1, 16); a1 += __shfl_xor(a1, 32);
        a2 += __shfl_xor(a2, 8);  a2 += __shfl_xor(a2, 16); a2 += __shfl_xor(a2, 32);
        a3 += __shfl_xor(a3, 8);  a3 += __shfl_xor(a3, 16); a3 += __shfl_xor(a3, 32);
        a4 += __shfl_xor(a4, 8);  a4 += __shfl_xor(a4, 16); a4 += __shfl_xor(a4, 32);
        a5 += __shfl_xor(a5, 8);  a5 += __shfl_xor(a5, 16); a5 += __shfl_xor(a5, 32);
        a6 += __shfl_xor(a6, 8);  a6 += __shfl_xor(a6, 16); a6 += __shfl_xor(a6, 32);
        a7 += __shfl_xor(a7, 8);  a7 += __shfl_xor(a7, 16); a7 += __shfl_xor(a7, 32);
        const int c = bb * 64 + nd;
        if (c < NN) {
            float d = dis[c];
            float coef = fmaf(d, w[nd], d * d);
            uint4 sv = *reinterpret_cast<const uint4*>(hs + ((size_t)c << 6) + (l8 << 3));
            float g0 = fmaf(d, a0 + h2f((ushort)(sv.x & 0xffffu)), blv0.x);
            float g1 = fmaf(d, a1 + h2f((ushort)(sv.x >> 16)),     blv0.y);
            float g2 = fmaf(d, a2 + h2f((ushort)(sv.y & 0xffffu)), blv0.z);
            float g3 = fmaf(d, a3 + h2f((ushort)(sv.y >> 16)),     blv0.w);
            float g4 = fmaf(d, a4 + h2f((ushort)(sv.z & 0xffffu)), blv1.x);
            float g5 = fmaf(d, a5 + h2f((ushort)(sv.z >> 16)),     blv1.y);
            float g6 = fmaf(d, a6 + h2f((ushort)(sv.w & 0xffffu)), blv1.z);
            float g7 = fmaf(d, a7 + h2f((ushort)(sv.w >> 16)),     blv1.w);
            s0a = fmaf(coef, fmaxf(g0, 0.f), s0a);
            s1a = fmaf(coef, fmaxf(g1, 0.f), s1a);
            s2a = fmaf(coef, fmaxf(g2, 0.f), s2a);
            s3a = fmaf(coef, fmaxf(g3, 0.f), s3a);
            s4a = fmaf(coef, fmaxf(g4, 0.f), s4a);
            s5a = fmaf(coef, fmaxf(g5, 0.f), s5a);
            s6a = fmaf(coef, fmaxf(g6, 0.f), s6a);
            s7a = fmaf(coef, fmaxf(g7, 0.f), s7a);
        }
    }
    if (g8 == 0) {
        red[wv][(l8 << 3) + 0] = s0a;
        red[wv][(l8 << 3) + 1] = s1a;
        red[wv][(l8 << 3) + 2] = s2a;
        red[wv][(l8 << 3) + 3] = s3a;
        red[wv][(l8 << 3) + 4] = s4a;
        red[wv][(l8 << 3) + 5] = s5a;
        red[wv][(l8 << 3) + 6] = s6a;
        red[wv][(l8 << 3) + 7] = s7a;
    }
    __syncthreads();
    if (wv == 0) {
        float s = ((red[0][lane] + red[1][lane]) + (red[2][lane] + red[3][lane])) +
                  ((red[4][lane] + red[5][lane]) + (red[6][lane] + red[7][lane]));
        atomicAdd(&svec[lane], s);
    }
}

// ---------------- output + fused finalize --------------------------------------
__global__ __launch_bounds__(256) void out_final(const float* __restrict__ H,
    const float* __restrict__ bnsum, const float* __restrict__ bnsumsq,
    const float* __restrict__ gamma, const float* __restrict__ beta,
    const float* __restrict__ svec, const float* __restrict__ g2W,
    const float* __restrict__ g2b, const float* __restrict__ fc1W,
    const float* __restrict__ fc1b, const float* __restrict__ fc2W,
    const float* __restrict__ fc2b, float* __restrict__ out)
{
    __shared__ float scaleS[64], shiftS[64], vdnnS[64];
    __shared__ float consS;
    const int tid = threadIdx.x;
    const int lane = tid & 63;
    const int grp = tid >> 6;
    if (tid < 64) {                              // wave 0 computes finalize
        int j = tid;
        float mu = bnsum[j] * (1.0f / NB);
        float var = bnsumsq[j] * (1.0f / NB) - mu * mu;
        float sc = rsqrtf(var + 1e-5f) * gamma[j];
        scaleS[j] = sc;
        shiftS[j] = beta[j] - mu * sc;
        float ge = 0.f;
        for (int k = 0; k < 64; ++k) ge += svec[k] * g2W[k * 64 + j];
        ge = ge * (1.0f / NN) + g2b[j];
        float vd = 0.f, vg = 0.f;
        for (int k = 0; k < 64; ++k) {
            vd += fc1W[j * 64 + k] * fc2W[k];
            vg += fc1W[(64 + j) * 64 + k] * fc2W[k];
        }
        vdnnS[j] = vd;
        float part = ge * vg + fc1b[j] * fc2W[j];
#pragma unroll
        for (int o = 32; o > 0; o >>= 1) part += __shfl_down(part, o);
        if (j == 0) consS = part + fc2b[0];
    }
    __syncthreads();
    const float sc = scaleS[lane], sh = shiftS[lane], vd = vdnnS[lane];
    const float C = consS;
#pragma unroll 1
    for (int t = 0; t < 8; ++t) {
        int i = blockIdx.x * 32 + grp * 8 + t;
        float x = H[(size_t)i * 64 + lane] * sc + sh;
        x = fmaxf(x, 0.f) * vd;
#pragma unroll
        for (int o = 32; o > 0; o >>= 1) x += __shfl_down(x, o);
        if (lane == 0) out[i] = x + C;
    }
}

extern "C" void kernel_launch(void* const* d_in, const int* in_sizes, int n_in,
                              void* d_out, int out_size, void* d_ws, size_t ws_size,
                              hipStream_t stream)
{
    const float* x1    = (const float*)d_in[0];
    const float* x2    = (const float*)d_in[1];
    const int*   ei    = (const int*)d_in[2];
    const float* dnnW  = (const float*)d_in[3];
    // d_in[4] = dnn_b: cancels inside BatchNorm, unused
    const float* gamma = (const float*)d_in[5];
    const float* beta  = (const float*)d_in[6];
    const float* g1W   = (const float*)d_in[7];
    const float* g1b   = (const float*)d_in[8];
    const float* g2W   = (const float*)d_in[9];
    const float* g2b   = (const float*)d_in[10];
    const float* fc1W  = (const float*)d_in[11];
    const float* fc1b  = (const float*)d_in[12];
    const float* fc2W  = (const float*)d_in[13];
    const float* fc2b  = (const float*)d_in[14];

    float* ws      = (float*)d_ws;
    ushort* h1h    = (ushort*)ws;                 // 50176*64 ushorts = 1,605,632 f
    float* hdnn    = ws + 1605632;                // 1,048,576 f
    float* dis     = hdnn + 1048576;              // 50,176 f
    int*   cnth    = (int*)(dis + 50176 + 25088); // 50,176 i (keeps old layout)
    uint*  bufC    = (uint*)(cnth + 50176);       // 784*1280 = 1,003,520
    uint*  bufR    = bufC + NBKT * BCAP;          // 1,003,520
    int*   gcurC   = (int*)(bufR + NBKT * BCAP);  // 784   <- zero region start
    int*   gcurR   = gcurC + NBKT;                // 784
    float* bnsum   = (float*)(gcurR + NBKT);      // 64
    float* bnsumsq = bnsum + 64;                  // 64
    float* svec    = bnsumsq + 64;                // 64    <- zero region end (1760)

    zero_kernel<<<1, 256, 0, stream>>>(gcurC, NBKT * 2 + 192);

    mega<<<P1B + DNNB + NBKT, 512, 0, stream>>>(ei, bufC, bufR, gcurC, gcurR,
                                                x1, dnnW, hdnn, bnsum, bnsumsq,
                                                x2, g1W, h1h);
    cnt_dis_scale<<<NBKT, 256, 0, stream>>>(bufC, gcurC, h1h, dis, cnth);
    gather_pass<<<NBKT, 512, 0, stream>>>(bufC, gcurC, cnth, bufR, gcurR,
                                          dis, h1h, g1b, svec);
    out_final<<<512, 256, 0, stream>>>(hdnn, bnsum, bnsumsq, gamma, beta, svec,
                                       g2W, g2b, fc1W, fc1b, fc2W, fc2b,
                                       (float*)d_out);
}